// Round 10
// baseline (18677.068 us; speedup 1.0000x reference)
//
#include <hip/hip_runtime.h>
#include <hip/hip_bf16.h>

typedef float f32x4 __attribute__((ext_vector_type(4)));
typedef __bf16 bf16x8 __attribute__((ext_vector_type(8)));

#define B_SZ 2048
#define T_IN 48
#define FEAT 64
#define UNITS 1024
#define GCOLS 4096   // 4*UNITS
#define OUT_STEPS 64
#define KWARM 1088   // UNITS + FEAT

// Gate-major column permutation: c' = 64*Bk + 16*g + u  (Bk = 64-col half-block, g = gate, u = unit-low)
// original (Keras i,f,g,o) column: oc = g*1024 + (Bk*16 + u)
__device__ __forceinline__ int oc_of(int c) {
    return (((c >> 4) & 3) * UNITS) + ((c >> 6) * 16) + (c & 15);
}

typedef __attribute__((address_space(1))) const void gas_t;
typedef __attribute__((address_space(3))) void las_t;

__device__ __forceinline__ void gl_lds16(const void* g, void* l) {
    __builtin_amdgcn_global_load_lds((gas_t*)g, (las_t*)l, 16, 0, 0);
}
__device__ __forceinline__ float sigm(float x) {
    return __builtin_amdgcn_rcpf(1.0f + __expf(-x));
}
__device__ __forceinline__ float tanh_fast(float x) {
    float e = __expf(2.0f * x);
    return 1.0f - 2.0f * __builtin_amdgcn_rcpf(e + 1.0f);
}

// ---------- precompute kernels (unchanged, correctness-proven) ----------

__global__ __launch_bounds__(256) void reorder_UW(const float* __restrict__ U, const float* __restrict__ W,
                                                  __hip_bfloat16* __restrict__ UTw) {
    __shared__ __hip_bfloat16 t[64][64];
    const int k0 = blockIdx.x * 64;   // 17 tiles
    const int c0 = blockIdx.y * 64;   // 64 tiles
    const int tid = threadIdx.x;
#pragma unroll
    for (int i = 0; i < 16; ++i) {
        int idx = tid + i * 256;
        int rk = idx >> 6, cc = idx & 63;
        int k = k0 + rk, c = c0 + cc;
        int oc = oc_of(c);
        float v = (k < UNITS) ? U[(size_t)k * GCOLS + oc] : W[(size_t)(k - UNITS) * GCOLS + oc];
        t[rk][cc] = __float2bfloat16(v);
    }
    __syncthreads();
#pragma unroll
    for (int i = 0; i < 16; ++i) {
        int idx = tid + i * 256;
        int rc = idx >> 6, kk = idx & 63;
        UTw[(size_t)(c0 + rc) * KWARM + k0 + kk] = t[kk][rc];
    }
}

__global__ __launch_bounds__(256) void transpose_Wd(const float* __restrict__ Wd, __hip_bfloat16* __restrict__ WdT) {
    __shared__ __hip_bfloat16 t[64][64];
    const int k0 = blockIdx.x * 64;  // 16 blocks
    const int tid = threadIdx.x;
#pragma unroll
    for (int i = 0; i < 16; ++i) {
        int idx = tid + i * 256;
        int rk = idx >> 6, ff = idx & 63;
        t[rk][ff] = __float2bfloat16(Wd[(size_t)(k0 + rk) * FEAT + ff]);
    }
    __syncthreads();
#pragma unroll
    for (int i = 0; i < 16; ++i) {
        int idx = tid + i * 256;
        int rf = idx >> 6, kk = idx & 63;
        WdT[(size_t)rf * UNITS + k0 + kk] = t[kk][rf];
    }
}

__global__ __launch_bounds__(256) void build_UTdec(const __hip_bfloat16* __restrict__ UTw,
                                                   const __hip_bfloat16* __restrict__ WdT,
                                                   __hip_bfloat16* __restrict__ UTd) {
    __shared__ float Wl[64][16];
    const int k = blockIdx.x * 256 + threadIdx.x;  // 4 blocks
    const int c0 = blockIdx.y * 16;                // 256 blocks
    const int tid = threadIdx.x;
#pragma unroll
    for (int i = 0; i < 4; ++i) {
        int idx = tid + i * 256;
        int f = idx >> 4, cc = idx & 15;
        Wl[f][cc] = __bfloat162float(UTw[(size_t)(c0 + cc) * KWARM + UNITS + f]);
    }
    __syncthreads();
    float acc[16];
#pragma unroll
    for (int cc = 0; cc < 16; ++cc) acc[cc] = 0.f;
    for (int f = 0; f < 64; ++f) {
        float wd = __bfloat162float(WdT[(size_t)f * UNITS + k]);
#pragma unroll
        for (int cc = 0; cc < 16; ++cc) acc[cc] += wd * Wl[f][cc];
    }
#pragma unroll
    for (int cc = 0; cc < 16; ++cc) {
        float uv = __bfloat162float(UTw[(size_t)(c0 + cc) * KWARM + k]);
        UTd[(size_t)(c0 + cc) * UNITS + k] = __float2bfloat16(uv + acc[cc]);
    }
}

__global__ __launch_bounds__(256) void build_bias(const float* __restrict__ b, const float* __restrict__ bd,
                                                  const __hip_bfloat16* __restrict__ UTw,
                                                  float* __restrict__ bw, float* __restrict__ bdc) {
    const int c = blockIdx.x * 256 + threadIdx.x;  // 16 blocks
    const int oc = oc_of(c);
    float base = b[oc];
    float s = 0.f;
    for (int f = 0; f < FEAT; ++f) s += bd[f] * __bfloat162float(UTw[(size_t)c * KWARM + UNITS + f]);
    bw[c] = base;
    bdc[c] = base + s;
}

__global__ void convert_x(const float* __restrict__ x, __hip_bfloat16* __restrict__ xb, int n) {
    int i = blockIdx.x * blockDim.x + threadIdx.x;
    if (i < n) xb[i] = __float2bfloat16(x[i]);
}

// ---------- fused LSTM step ----------
// R10 = R9 (BK=32, proven swizzle, counted vmcnt, 256-thread codegen) with
// M-tile 64: grid 32mb x 32nb = 1024 blocks -> 4 blocks/CU (R6/R9 were
// grid-limited to 2). Cross-block phase stagger hides the per-phase
// vmcnt/barrier stall. LDS 24KB dbuf (A 64x32, B 128x32). Wave-tile 32x64,
// acc[2][4]. Pred: each of the 4 waves does 1 MFMA for rows 32wr+16wc.
template <bool WARM, bool PRED>
__global__ __launch_bounds__(256) void lstm_step(
    const __hip_bfloat16* __restrict__ hin,          // [2048][1024]
    const __hip_bfloat16* __restrict__ xbf, int t,   // [2048][48][64] (WARM)
    const __hip_bfloat16* __restrict__ UT,           // [4096][KD]
    const float* __restrict__ bias,                  // [4096] (c'-indexed)
    float* __restrict__ cst,                         // [2048][1024]
    __hip_bfloat16* __restrict__ hout,               // [2048][1024]
    const __hip_bfloat16* __restrict__ WdT,          // [64][1024] (PRED)
    const float* __restrict__ bd,                    // [64] (PRED)
    float* __restrict__ out, int tstep)              // [2048][64][64] (PRED)
{
    constexpr int KD = WARM ? KWARM : UNITS;
    constexpr int NKT = KD / 32;          // 34 warm / 32 decode
    constexpr int NKT_U = UNITS / 32;     // 32: first x-tile index (warm)

    __shared__ alignas(16) __hip_bfloat16 Al[2 * 2048];   // 8 KB  (two 64x32 tiles)
    __shared__ alignas(16) __hip_bfloat16 Bl[2 * 4096];   // 16 KB (two 128x32 tiles)

    const int tid = threadIdx.x;
    const int lane = tid & 63;
    const int wv = tid >> 6;          // 0..3
    const int wr = wv >> 1;           // 0..1 (32-row halves of the 64-row tile)
    const int wc = wv & 1;            // 0..1 (64-col halves)
    const int bid = blockIdx.x;
    const int nb = bid & 31;          // fastest -> XCD round-robin keeps B L2-resident
    const int mb = bid >> 5;          // 0..31
    const int m0 = mb * 64;
    const int n0 = nb * 128;
    const bool doPred = PRED && (nb < 4);

    f32x4 acc[2][4] = {};
    f32x4 accp = {};

    // staging: chunk = 16 rows x 64B; lane -> row_in_chunk = lane>>2, 16B slot = lane&3
    const int r0 = lane >> 2;
    const int scol = (((lane & 3) ^ ((lane >> 3) & 3)) << 4);   // swizzled src byte col

    // A: 64x32 tile = 4 chunks, one per wave. B: 128x32 = 8 chunks, two per wave.
    const char* aS; const char* xS; const char* bS[2];
    {
        int arow = wv * 16 + r0;
        aS = (const char*)hin + (size_t)(m0 + arow) * (UNITS * 2) + scol;
        if (WARM) xS = (const char*)xbf + (size_t)(m0 + arow) * (T_IN * FEAT * 2) + (size_t)t * (FEAT * 2) + scol;
#pragma unroll
        for (int r = 0; r < 2; ++r) {
            int brow = (r * 4 + wv) * 16 + r0;
            bS[r] = (const char*)UT + (size_t)(n0 + brow) * (KD * 2) + scol;
        }
    }

    const int ar = lane & 15;
    const int q = lane >> 4;                      // k-slot 0..3 (8 elems each)
    const int rsl = (q ^ ((ar >> 1) & 3)) << 3;   // swizzled read slot (elems)

    // Wd fragments direct from global (L2-hot 128KB), one iter ahead in regs
    const char* wB = nullptr;
    if (PRED && doPred)
        wB = (const char*)WdT + ((size_t)(16 * nb + ar) * UNITS + q * 8) * 2;

    // epilogue geometry; bias preloaded (oldest VMEM ops, retired by first vmcnt)
    const int u16 = lane & 15;
    const int unit = (nb * 2 + wc) * 16 + u16;
    const int rbase = m0 + 32 * wr + (q << 2);
    float bv[4];
#pragma unroll
    for (int g = 0; g < 4; ++g) bv[g] = bias[n0 + 64 * wc + 16 * g + u16];
    float bdv = 0.f;
    if (PRED && doPred) bdv = bd[16 * nb + u16];

    auto stage = [&](int kt) {
        const int buf = kt & 1;
        const char* s;
        if (WARM && kt >= NKT_U) s = xS + (kt - NKT_U) * 64;
        else                     s = aS + kt * 64;
        gl_lds16(s, (char*)Al + buf * 4096 + wv * 1024);
#pragma unroll
        for (int r = 0; r < 2; ++r)
            gl_lds16(bS[r] + kt * 64, (char*)Bl + buf * 8192 + (r * 4 + wv) * 1024);
    };

    bf16x8 Wf[2];   // [kt&1]
    auto loadWf = [&](int kt) {
        if (PRED && doPred)
            Wf[kt & 1] = *reinterpret_cast<const bf16x8*>(wB + kt * 64);
    };

    auto compute = [&](int kt) {
        const int buf = kt & 1;
        bf16x8 af[2], bfr[4];
#pragma unroll
        for (int mi = 0; mi < 2; ++mi)
            af[mi] = *reinterpret_cast<const bf16x8*>(&Al[buf * 2048 + (32 * wr + 16 * mi + ar) * 32 + rsl]);
#pragma unroll
        for (int ni = 0; ni < 4; ++ni)
            bfr[ni] = *reinterpret_cast<const bf16x8*>(&Bl[buf * 4096 + (64 * wc + 16 * ni + ar) * 32 + rsl]);
#pragma unroll
        for (int mi = 0; mi < 2; ++mi)
#pragma unroll
            for (int ni = 0; ni < 4; ++ni)
                acc[mi][ni] = __builtin_amdgcn_mfma_f32_16x16x32_bf16(af[mi], bfr[ni], acc[mi][ni], 0, 0, 0);
        if (PRED && doPred)
            accp = __builtin_amdgcn_mfma_f32_16x16x32_bf16(af[wc], Wf[kt & 1], accp, 0, 0, 0);
    };

    // ---- fully-unrolled pipelined K loop: stage(kt+1) in flight over compute(kt) ----
    stage(0);
    loadWf(0);
#pragma unroll
    for (int kt = 0; kt < NKT - 1; ++kt) {
        stage(kt + 1);
        loadWf(kt + 1);
        // retire stage(kt) [+Wf(kt)]; keep stage(kt+1) [+Wf(kt+1)] in flight
        if (PRED && doPred) asm volatile("s_waitcnt vmcnt(4) lgkmcnt(0)" ::: "memory");
        else                asm volatile("s_waitcnt vmcnt(3) lgkmcnt(0)" ::: "memory");
        __builtin_amdgcn_s_barrier();
        compute(kt);
        __builtin_amdgcn_s_barrier();   // WAR: protect buf before next re-stage
    }
    // final iter: prefetch c-state in the slot where staging would be
    float cv[8];
#pragma unroll
    for (int mi = 0; mi < 2; ++mi)
#pragma unroll
        for (int reg = 0; reg < 4; ++reg)
            cv[mi * 4 + reg] = cst[(size_t)(rbase + 16 * mi + reg) * UNITS + unit];
    asm volatile("s_waitcnt vmcnt(8) lgkmcnt(0)" ::: "memory");
    __builtin_amdgcn_s_barrier();
    compute(NKT - 1);

    // ---- shuffle-free gate epilogue: acc[mi][g] are i,f,g,o of this lane's unit ----
#pragma unroll
    for (int mi = 0; mi < 2; ++mi)
#pragma unroll
        for (int reg = 0; reg < 4; ++reg) {
            float zi = acc[mi][0][reg] + bv[0];
            float zf = acc[mi][1][reg] + bv[1];
            float zg = acc[mi][2][reg] + bv[2];
            float zo = acc[mi][3][reg] + bv[3];
            float cn = sigm(zf) * cv[mi * 4 + reg] + sigm(zi) * tanh_fast(zg);
            size_t idx = (size_t)(rbase + 16 * mi + reg) * UNITS + unit;
            cst[idx] = cn;
            hout[idx] = __float2bfloat16(sigm(zo) * tanh_fast(cn));
        }

    if (PRED && doPred) {
        const int prow = m0 + 32 * wr + 16 * wc + (q << 2);
#pragma unroll
        for (int reg = 0; reg < 4; ++reg)
            out[(size_t)(prow + reg) * (OUT_STEPS * FEAT) + (size_t)tstep * FEAT + (16 * nb + u16)] = accp[reg] + bdv;
    }
}

// ---------- host ----------
extern "C" void kernel_launch(void* const* d_in, const int* in_sizes, int n_in,
                              void* d_out, int out_size, void* d_ws, size_t ws_size,
                              hipStream_t stream) {
    const float* inputs = (const float*)d_in[0];
    const float* W  = (const float*)d_in[1];
    const float* U  = (const float*)d_in[2];
    const float* b  = (const float*)d_in[3];
    const float* Wd = (const float*)d_in[4];
    const float* bd = (const float*)d_in[5];
    float* out = (float*)d_out;

    char* ws = (char*)d_ws;
    size_t off = 0;
    auto alloc = [&](size_t bytes) { char* p = ws + off; off = (off + bytes + 255) & ~255ULL; return p; };
    __hip_bfloat16* UTw = (__hip_bfloat16*)alloc((size_t)GCOLS * KWARM * 2);
    __hip_bfloat16* UTd = (__hip_bfloat16*)alloc((size_t)GCOLS * UNITS * 2);
    __hip_bfloat16* WdT = (__hip_bfloat16*)alloc((size_t)FEAT * UNITS * 2);
    __hip_bfloat16* Xbf = (__hip_bfloat16*)alloc((size_t)B_SZ * T_IN * FEAT * 2);
    __hip_bfloat16* hA  = (__hip_bfloat16*)alloc((size_t)B_SZ * UNITS * 2);
    __hip_bfloat16* hB  = (__hip_bfloat16*)alloc((size_t)B_SZ * UNITS * 2);
    float* cst = (float*)alloc((size_t)B_SZ * UNITS * 4);
    float* bw  = (float*)alloc(GCOLS * 4);
    float* bdc = (float*)alloc(GCOLS * 4);

    hipMemsetAsync(cst, 0, (size_t)B_SZ * UNITS * 4, stream);
    hipMemsetAsync(hA, 0, (size_t)B_SZ * UNITS * 2, stream);

    dim3 blk(256);
    reorder_UW<<<dim3(17, 64), blk, 0, stream>>>(U, W, UTw);
    transpose_Wd<<<dim3(16), blk, 0, stream>>>(Wd, WdT);
    build_UTdec<<<dim3(4, 256), blk, 0, stream>>>(UTw, WdT, UTd);
    build_bias<<<dim3(16), blk, 0, stream>>>(b, bd, UTw, bw, bdc);
    {
        int n = B_SZ * T_IN * FEAT;
        convert_x<<<dim3((n + 255) / 256), blk, 0, stream>>>(inputs, Xbf, n);
    }

    const __hip_bfloat16* cur = hA;
    __hip_bfloat16* nxt = hB;
    for (int t = 0; t < T_IN; ++t) {
        lstm_step<true, false><<<dim3(1024), blk, 0, stream>>>(cur, Xbf, t, UTw, bw, cst, nxt,
                                                               nullptr, nullptr, nullptr, 0);
        __hip_bfloat16* tmp = (__hip_bfloat16*)cur; cur = nxt; nxt = tmp;
    }
    // decode: kernel t consumes h_{t-1} (writes pred_{t-1}) and produces h_t
    for (int t = 1; t <= OUT_STEPS; ++t) {
        lstm_step<false, true><<<dim3(1024), blk, 0, stream>>>(cur, nullptr, 0, UTd, bdc, cst, nxt,
                                                               WdT, bd, out, t - 1);
        __hip_bfloat16* tmp = (__hip_bfloat16*)cur; cur = nxt; nxt = tmp;
    }
}

// Round 11
// 18591.489 us; speedup vs baseline: 1.0046x; 1.0046x over previous
//
#include <hip/hip_runtime.h>
#include <hip/hip_bf16.h>

typedef float f32x4 __attribute__((ext_vector_type(4)));
typedef __bf16 bf16x8 __attribute__((ext_vector_type(8)));

#define B_SZ 2048
#define T_IN 48
#define FEAT 64
#define UNITS 1024
#define GCOLS 4096   // 4*UNITS
#define OUT_STEPS 64
#define KWARM 1088   // UNITS + FEAT

// Gate-major column permutation: c' = 64*Bk + 16*g + u  (Bk = 64-col half-block, g = gate, u = unit-low)
// original (Keras i,f,g,o) column: oc = g*1024 + (Bk*16 + u)
__device__ __forceinline__ int oc_of(int c) {
    return (((c >> 4) & 3) * UNITS) + ((c >> 6) * 16) + (c & 15);
}

typedef __attribute__((address_space(1))) const void gas_t;
typedef __attribute__((address_space(3))) void las_t;

__device__ __forceinline__ void gl_lds16(const void* g, void* l) {
    __builtin_amdgcn_global_load_lds((gas_t*)g, (las_t*)l, 16, 0, 0);
}
__device__ __forceinline__ float sigm(float x) {
    return __builtin_amdgcn_rcpf(1.0f + __expf(-x));
}
__device__ __forceinline__ float tanh_fast(float x) {
    float e = __expf(2.0f * x);
    return 1.0f - 2.0f * __builtin_amdgcn_rcpf(e + 1.0f);
}

// ---------- precompute kernels (unchanged, correctness-proven) ----------

__global__ __launch_bounds__(256) void reorder_UW(const float* __restrict__ U, const float* __restrict__ W,
                                                  __hip_bfloat16* __restrict__ UTw) {
    __shared__ __hip_bfloat16 t[64][64];
    const int k0 = blockIdx.x * 64;   // 17 tiles
    const int c0 = blockIdx.y * 64;   // 64 tiles
    const int tid = threadIdx.x;
#pragma unroll
    for (int i = 0; i < 16; ++i) {
        int idx = tid + i * 256;
        int rk = idx >> 6, cc = idx & 63;
        int k = k0 + rk, c = c0 + cc;
        int oc = oc_of(c);
        float v = (k < UNITS) ? U[(size_t)k * GCOLS + oc] : W[(size_t)(k - UNITS) * GCOLS + oc];
        t[rk][cc] = __float2bfloat16(v);
    }
    __syncthreads();
#pragma unroll
    for (int i = 0; i < 16; ++i) {
        int idx = tid + i * 256;
        int rc = idx >> 6, kk = idx & 63;
        UTw[(size_t)(c0 + rc) * KWARM + k0 + kk] = t[kk][rc];
    }
}

__global__ __launch_bounds__(256) void transpose_Wd(const float* __restrict__ Wd, __hip_bfloat16* __restrict__ WdT) {
    __shared__ __hip_bfloat16 t[64][64];
    const int k0 = blockIdx.x * 64;  // 16 blocks
    const int tid = threadIdx.x;
#pragma unroll
    for (int i = 0; i < 16; ++i) {
        int idx = tid + i * 256;
        int rk = idx >> 6, ff = idx & 63;
        t[rk][ff] = __float2bfloat16(Wd[(size_t)(k0 + rk) * FEAT + ff]);
    }
    __syncthreads();
#pragma unroll
    for (int i = 0; i < 16; ++i) {
        int idx = tid + i * 256;
        int rf = idx >> 6, kk = idx & 63;
        WdT[(size_t)rf * UNITS + k0 + kk] = t[kk][rf];
    }
}

__global__ __launch_bounds__(256) void build_UTdec(const __hip_bfloat16* __restrict__ UTw,
                                                   const __hip_bfloat16* __restrict__ WdT,
                                                   __hip_bfloat16* __restrict__ UTd) {
    __shared__ float Wl[64][16];
    const int k = blockIdx.x * 256 + threadIdx.x;  // 4 blocks
    const int c0 = blockIdx.y * 16;                // 256 blocks
    const int tid = threadIdx.x;
#pragma unroll
    for (int i = 0; i < 4; ++i) {
        int idx = tid + i * 256;
        int f = idx >> 4, cc = idx & 15;
        Wl[f][cc] = __bfloat162float(UTw[(size_t)(c0 + cc) * KWARM + UNITS + f]);
    }
    __syncthreads();
    float acc[16];
#pragma unroll
    for (int cc = 0; cc < 16; ++cc) acc[cc] = 0.f;
    for (int f = 0; f < 64; ++f) {
        float wd = __bfloat162float(WdT[(size_t)f * UNITS + k]);
#pragma unroll
        for (int cc = 0; cc < 16; ++cc) acc[cc] += wd * Wl[f][cc];
    }
#pragma unroll
    for (int cc = 0; cc < 16; ++cc) {
        float uv = __bfloat162float(UTw[(size_t)(c0 + cc) * KWARM + k]);
        UTd[(size_t)(c0 + cc) * UNITS + k] = __float2bfloat16(uv + acc[cc]);
    }
}

__global__ __launch_bounds__(256) void build_bias(const float* __restrict__ b, const float* __restrict__ bd,
                                                  const __hip_bfloat16* __restrict__ UTw,
                                                  float* __restrict__ bw, float* __restrict__ bdc) {
    const int c = blockIdx.x * 256 + threadIdx.x;  // 16 blocks
    const int oc = oc_of(c);
    float base = b[oc];
    float s = 0.f;
    for (int f = 0; f < FEAT; ++f) s += bd[f] * __bfloat162float(UTw[(size_t)c * KWARM + UNITS + f]);
    bw[c] = base;
    bdc[c] = base + s;
}

__global__ void convert_x(const float* __restrict__ x, __hip_bfloat16* __restrict__ xb, int n) {
    int i = blockIdx.x * blockDim.x + threadIdx.x;
    if (i < n) xb[i] = __float2bfloat16(x[i]);
}

// ---------- fused LSTM step ----------
// R11 = R10 (64x128 tile, 1024 blocks = 4/CU, BK=32, counted vmcnt) with LDS
// PADDED 24->32KB (unused Bl tail). Evidence across R3-R10: hipcc's regalloc
// targets the occupancy LDS permits; at 24KB it clamped VGPR to 76 and
// serialized ds_read->MFMA (276us). 32KB reproduces R9's proven VGPR~124
// codegen while the 1024-block grid supplies the 4-block/CU stagger.
template <bool WARM, bool PRED>
__global__ __launch_bounds__(256) void lstm_step(
    const __hip_bfloat16* __restrict__ hin,          // [2048][1024]
    const __hip_bfloat16* __restrict__ xbf, int t,   // [2048][48][64] (WARM)
    const __hip_bfloat16* __restrict__ UT,           // [4096][KD]
    const float* __restrict__ bias,                  // [4096] (c'-indexed)
    float* __restrict__ cst,                         // [2048][1024]
    __hip_bfloat16* __restrict__ hout,               // [2048][1024]
    const __hip_bfloat16* __restrict__ WdT,          // [64][1024] (PRED)
    const float* __restrict__ bd,                    // [64] (PRED)
    float* __restrict__ out, int tstep)              // [2048][64][64] (PRED)
{
    constexpr int KD = WARM ? KWARM : UNITS;
    constexpr int NKT = KD / 32;          // 34 warm / 32 decode
    constexpr int NKT_U = UNITS / 32;     // 32: first x-tile index (warm)

    __shared__ alignas(16) __hip_bfloat16 Al[2 * 2048];          // 8 KB  (two 64x32 tiles)
    __shared__ alignas(16) __hip_bfloat16 Bl[2 * 4096 + 4096];   // 16 KB used + 8 KB pad -> block LDS 32 KB

    const int tid = threadIdx.x;
    const int lane = tid & 63;
    const int wv = tid >> 6;          // 0..3
    const int wr = wv >> 1;           // 0..1 (32-row halves of the 64-row tile)
    const int wc = wv & 1;            // 0..1 (64-col halves)
    const int bid = blockIdx.x;
    const int nb = bid & 31;          // fastest -> XCD round-robin keeps B L2-resident
    const int mb = bid >> 5;          // 0..31
    const int m0 = mb * 64;
    const int n0 = nb * 128;
    const bool doPred = PRED && (nb < 4);

    f32x4 acc[2][4] = {};
    f32x4 accp = {};

    // staging: chunk = 16 rows x 64B; lane -> row_in_chunk = lane>>2, 16B slot = lane&3
    const int r0 = lane >> 2;
    const int scol = (((lane & 3) ^ ((lane >> 3) & 3)) << 4);   // swizzled src byte col

    // A: 64x32 tile = 4 chunks, one per wave. B: 128x32 = 8 chunks, two per wave.
    const char* aS; const char* xS; const char* bS[2];
    {
        int arow = wv * 16 + r0;
        aS = (const char*)hin + (size_t)(m0 + arow) * (UNITS * 2) + scol;
        if (WARM) xS = (const char*)xbf + (size_t)(m0 + arow) * (T_IN * FEAT * 2) + (size_t)t * (FEAT * 2) + scol;
#pragma unroll
        for (int r = 0; r < 2; ++r) {
            int brow = (r * 4 + wv) * 16 + r0;
            bS[r] = (const char*)UT + (size_t)(n0 + brow) * (KD * 2) + scol;
        }
    }

    const int ar = lane & 15;
    const int q = lane >> 4;                      // k-slot 0..3 (8 elems each)
    const int rsl = (q ^ ((ar >> 1) & 3)) << 3;   // swizzled read slot (elems)

    // Wd fragments direct from global (L2-hot 128KB), one iter ahead in regs
    const char* wB = nullptr;
    if (PRED && doPred)
        wB = (const char*)WdT + ((size_t)(16 * nb + ar) * UNITS + q * 8) * 2;

    // epilogue geometry; bias preloaded (oldest VMEM ops, retired by first vmcnt)
    const int u16 = lane & 15;
    const int unit = (nb * 2 + wc) * 16 + u16;
    const int rbase = m0 + 32 * wr + (q << 2);
    float bv[4];
#pragma unroll
    for (int g = 0; g < 4; ++g) bv[g] = bias[n0 + 64 * wc + 16 * g + u16];
    float bdv = 0.f;
    if (PRED && doPred) bdv = bd[16 * nb + u16];

    auto stage = [&](int kt) {
        const int buf = kt & 1;
        const char* s;
        if (WARM && kt >= NKT_U) s = xS + (kt - NKT_U) * 64;
        else                     s = aS + kt * 64;
        gl_lds16(s, (char*)Al + buf * 4096 + wv * 1024);
#pragma unroll
        for (int r = 0; r < 2; ++r)
            gl_lds16(bS[r] + kt * 64, (char*)Bl + buf * 8192 + (r * 4 + wv) * 1024);
    };

    bf16x8 Wf[2];   // [kt&1]
    auto loadWf = [&](int kt) {
        if (PRED && doPred)
            Wf[kt & 1] = *reinterpret_cast<const bf16x8*>(wB + kt * 64);
    };

    auto compute = [&](int kt) {
        const int buf = kt & 1;
        bf16x8 af[2], bfr[4];
#pragma unroll
        for (int mi = 0; mi < 2; ++mi)
            af[mi] = *reinterpret_cast<const bf16x8*>(&Al[buf * 2048 + (32 * wr + 16 * mi + ar) * 32 + rsl]);
#pragma unroll
        for (int ni = 0; ni < 4; ++ni)
            bfr[ni] = *reinterpret_cast<const bf16x8*>(&Bl[buf * 4096 + (64 * wc + 16 * ni + ar) * 32 + rsl]);
#pragma unroll
        for (int mi = 0; mi < 2; ++mi)
#pragma unroll
            for (int ni = 0; ni < 4; ++ni)
                acc[mi][ni] = __builtin_amdgcn_mfma_f32_16x16x32_bf16(af[mi], bfr[ni], acc[mi][ni], 0, 0, 0);
        if (PRED && doPred)
            accp = __builtin_amdgcn_mfma_f32_16x16x32_bf16(af[wc], Wf[kt & 1], accp, 0, 0, 0);
    };

    // ---- fully-unrolled pipelined K loop: stage(kt+1) in flight over compute(kt) ----
    stage(0);
    loadWf(0);
#pragma unroll
    for (int kt = 0; kt < NKT - 1; ++kt) {
        stage(kt + 1);
        loadWf(kt + 1);
        // retire stage(kt) [+Wf(kt)]; keep stage(kt+1) [+Wf(kt+1)] in flight
        if (PRED && doPred) asm volatile("s_waitcnt vmcnt(4) lgkmcnt(0)" ::: "memory");
        else                asm volatile("s_waitcnt vmcnt(3) lgkmcnt(0)" ::: "memory");
        __builtin_amdgcn_s_barrier();
        compute(kt);
        __builtin_amdgcn_s_barrier();   // WAR: protect buf before next re-stage
    }
    // final iter: prefetch c-state in the slot where staging would be
    float cv[8];
#pragma unroll
    for (int mi = 0; mi < 2; ++mi)
#pragma unroll
        for (int reg = 0; reg < 4; ++reg)
            cv[mi * 4 + reg] = cst[(size_t)(rbase + 16 * mi + reg) * UNITS + unit];
    asm volatile("s_waitcnt vmcnt(8) lgkmcnt(0)" ::: "memory");
    __builtin_amdgcn_s_barrier();
    compute(NKT - 1);

    // ---- shuffle-free gate epilogue: acc[mi][g] are i,f,g,o of this lane's unit ----
#pragma unroll
    for (int mi = 0; mi < 2; ++mi)
#pragma unroll
        for (int reg = 0; reg < 4; ++reg) {
            float zi = acc[mi][0][reg] + bv[0];
            float zf = acc[mi][1][reg] + bv[1];
            float zg = acc[mi][2][reg] + bv[2];
            float zo = acc[mi][3][reg] + bv[3];
            float cn = sigm(zf) * cv[mi * 4 + reg] + sigm(zi) * tanh_fast(zg);
            size_t idx = (size_t)(rbase + 16 * mi + reg) * UNITS + unit;
            cst[idx] = cn;
            hout[idx] = __float2bfloat16(sigm(zo) * tanh_fast(cn));
        }

    if (PRED && doPred) {
        const int prow = m0 + 32 * wr + 16 * wc + (q << 2);
#pragma unroll
        for (int reg = 0; reg < 4; ++reg)
            out[(size_t)(prow + reg) * (OUT_STEPS * FEAT) + (size_t)tstep * FEAT + (16 * nb + u16)] = accp[reg] + bdv;
    }
}

// ---------- host ----------
extern "C" void kernel_launch(void* const* d_in, const int* in_sizes, int n_in,
                              void* d_out, int out_size, void* d_ws, size_t ws_size,
                              hipStream_t stream) {
    const float* inputs = (const float*)d_in[0];
    const float* W  = (const float*)d_in[1];
    const float* U  = (const float*)d_in[2];
    const float* b  = (const float*)d_in[3];
    const float* Wd = (const float*)d_in[4];
    const float* bd = (const float*)d_in[5];
    float* out = (float*)d_out;

    char* ws = (char*)d_ws;
    size_t off = 0;
    auto alloc = [&](size_t bytes) { char* p = ws + off; off = (off + bytes + 255) & ~255ULL; return p; };
    __hip_bfloat16* UTw = (__hip_bfloat16*)alloc((size_t)GCOLS * KWARM * 2);
    __hip_bfloat16* UTd = (__hip_bfloat16*)alloc((size_t)GCOLS * UNITS * 2);
    __hip_bfloat16* WdT = (__hip_bfloat16*)alloc((size_t)FEAT * UNITS * 2);
    __hip_bfloat16* Xbf = (__hip_bfloat16*)alloc((size_t)B_SZ * T_IN * FEAT * 2);
    __hip_bfloat16* hA  = (__hip_bfloat16*)alloc((size_t)B_SZ * UNITS * 2);
    __hip_bfloat16* hB  = (__hip_bfloat16*)alloc((size_t)B_SZ * UNITS * 2);
    float* cst = (float*)alloc((size_t)B_SZ * UNITS * 4);
    float* bw  = (float*)alloc(GCOLS * 4);
    float* bdc = (float*)alloc(GCOLS * 4);

    hipMemsetAsync(cst, 0, (size_t)B_SZ * UNITS * 4, stream);
    hipMemsetAsync(hA, 0, (size_t)B_SZ * UNITS * 2, stream);

    dim3 blk(256);
    reorder_UW<<<dim3(17, 64), blk, 0, stream>>>(U, W, UTw);
    transpose_Wd<<<dim3(16), blk, 0, stream>>>(Wd, WdT);
    build_UTdec<<<dim3(4, 256), blk, 0, stream>>>(UTw, WdT, UTd);
    build_bias<<<dim3(16), blk, 0, stream>>>(b, bd, UTw, bw, bdc);
    {
        int n = B_SZ * T_IN * FEAT;
        convert_x<<<dim3((n + 255) / 256), blk, 0, stream>>>(inputs, Xbf, n);
    }

    const __hip_bfloat16* cur = hA;
    __hip_bfloat16* nxt = hB;
    for (int t = 0; t < T_IN; ++t) {
        lstm_step<true, false><<<dim3(1024), blk, 0, stream>>>(cur, Xbf, t, UTw, bw, cst, nxt,
                                                               nullptr, nullptr, nullptr, 0);
        __hip_bfloat16* tmp = (__hip_bfloat16*)cur; cur = nxt; nxt = tmp;
    }
    // decode: kernel t consumes h_{t-1} (writes pred_{t-1}) and produces h_t
    for (int t = 1; t <= OUT_STEPS; ++t) {
        lstm_step<false, true><<<dim3(1024), blk, 0, stream>>>(cur, nullptr, 0, UTd, bdc, cst, nxt,
                                                               WdT, bd, out, t - 1);
        __hip_bfloat16* tmp = (__hip_bfloat16*)cur; cur = nxt; nxt = tmp;
    }
}

// Round 12
// 4902.315 us; speedup vs baseline: 3.8098x; 3.7924x over previous
//
#include <hip/hip_runtime.h>
#include <hip/hip_bf16.h>

typedef float f32x4 __attribute__((ext_vector_type(4)));
typedef __bf16 bf16x8 __attribute__((ext_vector_type(8)));

#define B_SZ 2048
#define T_IN 48
#define FEAT 64
#define UNITS 1024
#define GCOLS 4096   // 4*UNITS
#define OUT_STEPS 64
#define KWARM 1088   // UNITS + FEAT

// Gate-major column permutation: c' = 64*Bk + 16*g + u  (Bk = 64-col half-block, g = gate, u = unit-low)
// original (Keras i,f,g,o) column: oc = g*1024 + (Bk*16 + u)
__device__ __forceinline__ int oc_of(int c) {
    return (((c >> 4) & 3) * UNITS) + ((c >> 6) * 16) + (c & 15);
}

typedef __attribute__((address_space(1))) const void gas_t;
typedef __attribute__((address_space(3))) void las_t;

__device__ __forceinline__ void gl_lds16(const void* g, void* l) {
    __builtin_amdgcn_global_load_lds((gas_t*)g, (las_t*)l, 16, 0, 0);
}
__device__ __forceinline__ float sigm(float x) {
    return __builtin_amdgcn_rcpf(1.0f + __expf(-x));
}
__device__ __forceinline__ float tanh_fast(float x) {
    float e = __expf(2.0f * x);
    return 1.0f - 2.0f * __builtin_amdgcn_rcpf(e + 1.0f);
}

// ---------- precompute kernels (unchanged, correctness-proven) ----------

__global__ __launch_bounds__(256) void reorder_UW(const float* __restrict__ U, const float* __restrict__ W,
                                                  __hip_bfloat16* __restrict__ UTw) {
    __shared__ __hip_bfloat16 t[64][64];
    const int k0 = blockIdx.x * 64;   // 17 tiles
    const int c0 = blockIdx.y * 64;   // 64 tiles
    const int tid = threadIdx.x;
#pragma unroll
    for (int i = 0; i < 16; ++i) {
        int idx = tid + i * 256;
        int rk = idx >> 6, cc = idx & 63;
        int k = k0 + rk, c = c0 + cc;
        int oc = oc_of(c);
        float v = (k < UNITS) ? U[(size_t)k * GCOLS + oc] : W[(size_t)(k - UNITS) * GCOLS + oc];
        t[rk][cc] = __float2bfloat16(v);
    }
    __syncthreads();
#pragma unroll
    for (int i = 0; i < 16; ++i) {
        int idx = tid + i * 256;
        int rc = idx >> 6, kk = idx & 63;
        UTw[(size_t)(c0 + rc) * KWARM + k0 + kk] = t[kk][rc];
    }
}

__global__ __launch_bounds__(256) void transpose_Wd(const float* __restrict__ Wd, __hip_bfloat16* __restrict__ WdT) {
    __shared__ __hip_bfloat16 t[64][64];
    const int k0 = blockIdx.x * 64;  // 16 blocks
    const int tid = threadIdx.x;
#pragma unroll
    for (int i = 0; i < 16; ++i) {
        int idx = tid + i * 256;
        int rk = idx >> 6, ff = idx & 63;
        t[rk][ff] = __float2bfloat16(Wd[(size_t)(k0 + rk) * FEAT + ff]);
    }
    __syncthreads();
#pragma unroll
    for (int i = 0; i < 16; ++i) {
        int idx = tid + i * 256;
        int rf = idx >> 6, kk = idx & 63;
        WdT[(size_t)rf * UNITS + k0 + kk] = t[kk][rf];
    }
}

__global__ __launch_bounds__(256) void build_UTdec(const __hip_bfloat16* __restrict__ UTw,
                                                   const __hip_bfloat16* __restrict__ WdT,
                                                   __hip_bfloat16* __restrict__ UTd) {
    __shared__ float Wl[64][16];
    const int k = blockIdx.x * 256 + threadIdx.x;  // 4 blocks
    const int c0 = blockIdx.y * 16;                // 256 blocks
    const int tid = threadIdx.x;
#pragma unroll
    for (int i = 0; i < 4; ++i) {
        int idx = tid + i * 256;
        int f = idx >> 4, cc = idx & 15;
        Wl[f][cc] = __bfloat162float(UTw[(size_t)(c0 + cc) * KWARM + UNITS + f]);
    }
    __syncthreads();
    float acc[16];
#pragma unroll
    for (int cc = 0; cc < 16; ++cc) acc[cc] = 0.f;
    for (int f = 0; f < 64; ++f) {
        float wd = __bfloat162float(WdT[(size_t)f * UNITS + k]);
#pragma unroll
        for (int cc = 0; cc < 16; ++cc) acc[cc] += wd * Wl[f][cc];
    }
#pragma unroll
    for (int cc = 0; cc < 16; ++cc) {
        float uv = __bfloat162float(UTw[(size_t)(c0 + cc) * KWARM + k]);
        UTd[(size_t)(c0 + cc) * UNITS + k] = __float2bfloat16(uv + acc[cc]);
    }
}

__global__ __launch_bounds__(256) void build_bias(const float* __restrict__ b, const float* __restrict__ bd,
                                                  const __hip_bfloat16* __restrict__ UTw,
                                                  float* __restrict__ bw, float* __restrict__ bdc) {
    const int c = blockIdx.x * 256 + threadIdx.x;  // 16 blocks
    const int oc = oc_of(c);
    float base = b[oc];
    float s = 0.f;
    for (int f = 0; f < FEAT; ++f) s += bd[f] * __bfloat162float(UTw[(size_t)c * KWARM + UNITS + f]);
    bw[c] = base;
    bdc[c] = base + s;
}

__global__ void convert_x(const float* __restrict__ x, __hip_bfloat16* __restrict__ xb, int n) {
    int i = blockIdx.x * blockDim.x + threadIdx.x;
    if (i < n) xb[i] = __float2bfloat16(x[i]);
}

// ---------- fused LSTM step ----------
// R12 = R6 byte-identical EXCEPT the bid->(mb,nb) mapping: 8mb x 8nb rectangle
// per XCD (x = bid&7 is the XCD under round-robin dispatch). Per-XCD working
// set = 8 A-slices (2MB) + 8 B-slices (2MB) = 4MB = L2 capacity, and all 64
// blocks of the rectangle are co-resident (2/CU) -> A is fetched from L3 once
// per XCD (16MB/step, was ~128MB with linear mapping where A thrashed L2).
// Theory: steps are L3-BW-bound (~150MB/step at ~3.5-4 TB/s = measured 42us).
template <bool WARM, bool PRED>
__global__ __launch_bounds__(256) void lstm_step(
    const __hip_bfloat16* __restrict__ hin,          // [2048][1024]
    const __hip_bfloat16* __restrict__ xbf, int t,   // [2048][48][64] (WARM)
    const __hip_bfloat16* __restrict__ UT,           // [4096][KD]
    const float* __restrict__ bias,                  // [4096] (c'-indexed)
    float* __restrict__ cst,                         // [2048][1024]
    __hip_bfloat16* __restrict__ hout,               // [2048][1024]
    const __hip_bfloat16* __restrict__ WdT,          // [64][1024] (PRED)
    const float* __restrict__ bd,                    // [64] (PRED)
    float* __restrict__ out, int tstep)              // [2048][64][64] (PRED)
{
    constexpr int KD = WARM ? KWARM : UNITS;
    constexpr int NKT = KD / 64;

    __shared__ alignas(16) __hip_bfloat16 Al[2 * 8192];   // 32 KB
    __shared__ alignas(16) __hip_bfloat16 Bl[2 * 8192];   // 32 KB

    const int tid = threadIdx.x;
    const int lane = tid & 63;
    const int wv = tid >> 6;
    const int wr = wv >> 1, wc = wv & 1;
    const int bid = blockIdx.x;
    // 8mb x 8nb rectangle per XCD: A-slice 2MB + B-slice 2MB fits the 4MB L2.
    const int x = bid & 7;            // XCD (round-robin dispatch)
    const int i6 = bid >> 3;          // 0..63 within XCD
    const int mb = ((x >> 2) << 3) + (i6 >> 3);   // 0..15
    const int nb = ((x & 3) << 3) + (i6 & 7);     // 0..31
    const int m0 = mb * 128;
    const int n0 = nb * 128;
    const bool doPred = PRED && (nb < 4);

    f32x4 acc[4][4] = {};
    f32x4 accp[2] = {};

    const int lrow = lane >> 3;
    const int scol = ((lane & 7) * 16) ^ (lrow << 4);   // swizzled source byte col

    // loop-invariant staging bases (k-advance folds into imm offsets)
    const char* aS[4]; const char* bS[4]; const char* xS[4];
#pragma unroll
    for (int r = 0; r < 4; ++r) {
        int row = (r * 4 + wv) * 8 + lrow;
        aS[r] = (const char*)hin + (size_t)(m0 + row) * (UNITS * 2) + scol;
        bS[r] = (const char*)UT + (size_t)(n0 + row) * (KD * 2) + scol;
        if (WARM) xS[r] = (const char*)xbf + (size_t)(m0 + row) * (T_IN * FEAT * 2) + (size_t)t * (FEAT * 2) + scol;
    }

    const int ar = lane & 15;
    const int ko = (lane >> 4) << 3;
    const int swz = (ar & 7) << 3;

    // Wd fragments direct from global (L2-hot 128KB), one iter ahead in regs
    const char* wB = nullptr;
    if (PRED && doPred)
        wB = (const char*)WdT + ((size_t)(16 * nb + ar) * UNITS + ko) * 2;

    // epilogue geometry; bias preloaded (oldest VMEM ops, retired by first vmcnt)
    const int u16 = lane & 15;
    const int unit = (nb * 2 + wc) * 16 + u16;
    const int rbase = m0 + 64 * wr + ((lane >> 4) << 2);
    float bv[4];
#pragma unroll
    for (int g = 0; g < 4; ++g) bv[g] = bias[n0 + 64 * wc + 16 * g + u16];
    float bdv = 0.f;
    if (PRED && doPred) bdv = bd[16 * nb + u16];

    auto stage = [&](int kt) {
        const int buf = kt & 1;
#pragma unroll
        for (int r = 0; r < 4; ++r) {
            const char* s = (WARM && kt == NKT - 1) ? xS[r] : (aS[r] + kt * 128);
            gl_lds16(s, (char*)Al + buf * 16384 + (r * 4 + wv) * 1024);
        }
#pragma unroll
        for (int r = 0; r < 4; ++r)
            gl_lds16(bS[r] + kt * 128, (char*)Bl + buf * 16384 + (r * 4 + wv) * 1024);
    };

    bf16x8 Wf[2][2];   // [kt&1][kk]
    auto loadWf = [&](int kt) {
        if (PRED && doPred) {
#pragma unroll
            for (int kk = 0; kk < 2; ++kk)
                Wf[kt & 1][kk] = *reinterpret_cast<const bf16x8*>(wB + kt * 128 + kk * 64);
        }
    };

    auto compute = [&](int kt) {
        const int buf = kt & 1;
#pragma unroll
        for (int kk = 0; kk < 2; ++kk) {
            bf16x8 af[4], bfr[4];
#pragma unroll
            for (int mi = 0; mi < 4; ++mi)
                af[mi] = *reinterpret_cast<const bf16x8*>(&Al[buf * 8192 + (64 * wr + 16 * mi + ar) * 64 + ((32 * kk + ko) ^ swz)]);
#pragma unroll
            for (int ni = 0; ni < 4; ++ni)
                bfr[ni] = *reinterpret_cast<const bf16x8*>(&Bl[buf * 8192 + (64 * wc + 16 * ni + ar) * 64 + ((32 * kk + ko) ^ swz)]);
#pragma unroll
            for (int mi = 0; mi < 4; ++mi)
#pragma unroll
                for (int ni = 0; ni < 4; ++ni)
                    acc[mi][ni] = __builtin_amdgcn_mfma_f32_16x16x32_bf16(af[mi], bfr[ni], acc[mi][ni], 0, 0, 0);
            if (PRED && doPred) {
#pragma unroll
                for (int pi = 0; pi < 2; ++pi)
                    accp[pi] = __builtin_amdgcn_mfma_f32_16x16x32_bf16(af[2 * wc + pi], Wf[kt & 1][kk], accp[pi], 0, 0, 0);
            }
        }
    };

    // ---- fully-unrolled pipelined K loop: stage(kt+1) in flight over compute(kt) ----
    stage(0);
    loadWf(0);
#pragma unroll
    for (int kt = 0; kt < NKT - 1; ++kt) {
        stage(kt + 1);
        loadWf(kt + 1);
        // retire stage(kt) [+Wf(kt)]; keep stage(kt+1) [+Wf(kt+1)] in flight
        if (PRED && doPred) asm volatile("s_waitcnt vmcnt(10) lgkmcnt(0)" ::: "memory");
        else                asm volatile("s_waitcnt vmcnt(8) lgkmcnt(0)" ::: "memory");
        __builtin_amdgcn_s_barrier();
        compute(kt);
        __builtin_amdgcn_s_barrier();   // WAR: protect buf before next re-stage
    }
    // final iter: prefetch c-state in the slot where staging would be
    float cv[16];
#pragma unroll
    for (int mi = 0; mi < 4; ++mi)
#pragma unroll
        for (int reg = 0; reg < 4; ++reg)
            cv[mi * 4 + reg] = cst[(size_t)(rbase + 16 * mi + reg) * UNITS + unit];
    asm volatile("s_waitcnt vmcnt(16) lgkmcnt(0)" ::: "memory");
    __builtin_amdgcn_s_barrier();
    compute(NKT - 1);

    // ---- shuffle-free gate epilogue: acc[mi][g] are i,f,g,o of this lane's unit ----
#pragma unroll
    for (int mi = 0; mi < 4; ++mi)
#pragma unroll
        for (int reg = 0; reg < 4; ++reg) {
            float zi = acc[mi][0][reg] + bv[0];
            float zf = acc[mi][1][reg] + bv[1];
            float zg = acc[mi][2][reg] + bv[2];
            float zo = acc[mi][3][reg] + bv[3];
            float cn = sigm(zf) * cv[mi * 4 + reg] + sigm(zi) * tanh_fast(zg);
            size_t idx = (size_t)(rbase + 16 * mi + reg) * UNITS + unit;
            cst[idx] = cn;
            hout[idx] = __float2bfloat16(sigm(zo) * tanh_fast(cn));
        }

    if (PRED && doPred) {
#pragma unroll
        for (int pi = 0; pi < 2; ++pi) {
            const int prow = m0 + 64 * wr + 32 * wc + 16 * pi + ((lane >> 4) << 2);
            f32x4 v = accp[pi];
#pragma unroll
            for (int reg = 0; reg < 4; ++reg)
                out[(size_t)(prow + reg) * (OUT_STEPS * FEAT) + (size_t)tstep * FEAT + (16 * nb + u16)] = v[reg] + bdv;
        }
    }
}

// ---------- host ----------
extern "C" void kernel_launch(void* const* d_in, const int* in_sizes, int n_in,
                              void* d_out, int out_size, void* d_ws, size_t ws_size,
                              hipStream_t stream) {
    const float* inputs = (const float*)d_in[0];
    const float* W  = (const float*)d_in[1];
    const float* U  = (const float*)d_in[2];
    const float* b  = (const float*)d_in[3];
    const float* Wd = (const float*)d_in[4];
    const float* bd = (const float*)d_in[5];
    float* out = (float*)d_out;

    char* ws = (char*)d_ws;
    size_t off = 0;
    auto alloc = [&](size_t bytes) { char* p = ws + off; off = (off + bytes + 255) & ~255ULL; return p; };
    __hip_bfloat16* UTw = (__hip_bfloat16*)alloc((size_t)GCOLS * KWARM * 2);
    __hip_bfloat16* UTd = (__hip_bfloat16*)alloc((size_t)GCOLS * UNITS * 2);
    __hip_bfloat16* WdT = (__hip_bfloat16*)alloc((size_t)FEAT * UNITS * 2);
    __hip_bfloat16* Xbf = (__hip_bfloat16*)alloc((size_t)B_SZ * T_IN * FEAT * 2);
    __hip_bfloat16* hA  = (__hip_bfloat16*)alloc((size_t)B_SZ * UNITS * 2);
    __hip_bfloat16* hB  = (__hip_bfloat16*)alloc((size_t)B_SZ * UNITS * 2);
    float* cst = (float*)alloc((size_t)B_SZ * UNITS * 4);
    float* bw  = (float*)alloc(GCOLS * 4);
    float* bdc = (float*)alloc(GCOLS * 4);

    hipMemsetAsync(cst, 0, (size_t)B_SZ * UNITS * 4, stream);
    hipMemsetAsync(hA, 0, (size_t)B_SZ * UNITS * 2, stream);

    dim3 blk(256);
    reorder_UW<<<dim3(17, 64), blk, 0, stream>>>(U, W, UTw);
    transpose_Wd<<<dim3(16), blk, 0, stream>>>(Wd, WdT);
    build_UTdec<<<dim3(4, 256), blk, 0, stream>>>(UTw, WdT, UTd);
    build_bias<<<dim3(16), blk, 0, stream>>>(b, bd, UTw, bw, bdc);
    {
        int n = B_SZ * T_IN * FEAT;
        convert_x<<<dim3((n + 255) / 256), blk, 0, stream>>>(inputs, Xbf, n);
    }

    const __hip_bfloat16* cur = hA;
    __hip_bfloat16* nxt = hB;
    for (int t = 0; t < T_IN; ++t) {
        lstm_step<true, false><<<dim3(512), blk, 0, stream>>>(cur, Xbf, t, UTw, bw, cst, nxt,
                                                              nullptr, nullptr, nullptr, 0);
        __hip_bfloat16* tmp = (__hip_bfloat16*)cur; cur = nxt; nxt = tmp;
    }
    // decode: kernel t consumes h_{t-1} (writes pred_{t-1}) and produces h_t
    for (int t = 1; t <= OUT_STEPS; ++t) {
        lstm_step<false, true><<<dim3(512), blk, 0, stream>>>(cur, nullptr, 0, UTd, bdc, cst, nxt,
                                                              WdT, bd, out, t - 1);
        __hip_bfloat16* tmp = (__hip_bfloat16*)cur; cur = nxt; nxt = tmp;
    }
}